// Round 1
// baseline (867.842 us; speedup 1.0000x reference)
//
#include <hip/hip_runtime.h>
#include <math.h>

#define NB 256
#define NN 1001
#define DD 128
#define SP 1008   // padded score row stride

__device__ __forceinline__ float wsum(float v) {
  #pragma unroll
  for (int off = 32; off > 0; off >>= 1) v += __shfl_xor(v, off, 64);
  return v;
}
__device__ __forceinline__ float wmax(float v) {
  #pragma unroll
  for (int off = 32; off > 0; off >>= 1) v = fmaxf(v, __shfl_xor(v, off, 64));
  return v;
}

// out[j] = bias[j] + sum_i in[i]*Wm[i*128+j]  (+res[j]) (relu optional)
// 256 threads: j = t&127, i-range split by t>>7. Coalesced W column reads.
__device__ void matvec(const float* __restrict__ Wm, const float* __restrict__ bias,
                       const float* in_s, const float* res_s, float* out_s,
                       float* part, int t, bool relu) {
  const int j = t & 127;
  const int half = t >> 7;
  const float* __restrict__ col = Wm + (size_t)half * 64 * DD + j;
  const float* in = in_s + half * 64;
  float acc = 0.f;
  #pragma unroll 8
  for (int i = 0; i < 64; ++i) acc = fmaf(in[i], col[(size_t)i * DD], acc);
  part[t] = acc;
  __syncthreads();
  if (t < 128) {
    float v = part[t] + part[t + 128] + bias[t];
    if (res_s) v += res_s[t];
    if (relu) v = fmaxf(v, 0.f);
    out_s[t] = v;
  }
  __syncthreads();
}

// h_s = LN(t_s)*g + b over 128 elems (biased var, eps 1e-5)
__device__ void lnorm(const float* t_s, float* h_s, const float* __restrict__ g,
                      const float* __restrict__ bb, float* red, int t) {
  const int wid = t >> 6, lane = t & 63;
  float x = (t < 128) ? t_s[t] : 0.f;
  float s = wsum(x);
  if (lane == 0) red[wid] = s;
  __syncthreads();
  float mean = (red[0] + red[1] + red[2] + red[3]) * (1.f / 128.f);
  float d = (t < 128) ? (x - mean) : 0.f;
  float s2 = wsum(d * d);
  if (lane == 0) red[4 + wid] = s2;
  __syncthreads();
  float var = (red[4] + red[5] + red[6] + red[7]) * (1.f / 128.f);
  if (t < 128) h_s[t] = d * rsqrtf(var + 1e-5f) * g[t] + bb[t];
  __syncthreads();
}

extern "C" __global__ void __launch_bounds__(256)
attn_model_kernel(const float* __restrict__ h_t, const float* __restrict__ K_att,
                  const float* __restrict__ V_att, const int* __restrict__ mask,
                  const float* __restrict__ W, const float* __restrict__ bW,
                  const float* __restrict__ ln_g, const float* __restrict__ ln_b,
                  const float* __restrict__ Wq, const float* __restrict__ bq,
                  float* __restrict__ out) {
  __shared__ __align__(16) float scores[8 * SP];   // 32.2 KB; row 0 reused for final scores
  __shared__ float h_s[DD], q_s[DD], tmp_s[DD], t_s[DD];
  __shared__ float part[256];
  __shared__ __align__(16) float vred[8 * DD];
  __shared__ float red[8];
  __shared__ float hsum[8];

  const int t = threadIdx.x;
  const int b = blockIdx.x;
  const int wid = t >> 6, lane = t & 63;

  if (t < 128) h_s[t] = h_t[(size_t)b * DD + t];
  __syncthreads();

  const int* __restrict__ mb = mask + (size_t)b * NN;

  for (int l = 0; l < 2; ++l) {
    const float* Wl = W + (size_t)l * 8 * DD * DD;
    const float* bl = bW + (size_t)l * 8 * DD;

    // self-attn with S=1 collapses: sa = v_sa = h@W2+b2
    matvec(Wl + 2 * DD * DD, bl + 2 * DD, h_s, nullptr, tmp_s, part, t, false);
    // t1 = h + v_sa@W3 + b3 ; h = LN(t1)
    matvec(Wl + 3 * DD * DD, bl + 3 * DD, tmp_s, h_s, t_s, part, t, false);
    lnorm(t_s, h_s, ln_g + (l * 3 + 0) * DD, ln_b + (l * 3 + 0) * DD, red, t);
    // q = h@W4 + b4
    matvec(Wl + 4 * DD * DD, bl + 4 * DD, h_s, nullptr, q_s, part, t, false);

    // ---- 8-head cross attention, single query, K/V rows stride 384 floats ----
    const float* Kb = K_att + (size_t)b * NN * 384 + l * DD;
    const float* Vb = V_att + (size_t)b * NN * 384 + l * DD;
    {
      // Phase A: scores. thread -> (row = t>>3, head = t&7)
      const int nl0 = t >> 3, hh = t & 7;
      float qr[16];
      #pragma unroll
      for (int k = 0; k < 16; ++k) qr[k] = q_s[hh * 16 + k];
      for (int base = 0; base < 1024; base += 32) {
        int n = base + nl0;
        if (n < NN) {
          const float4* kr = (const float4*)(Kb + (size_t)n * 384 + hh * 16);
          float4 a0 = kr[0], a1 = kr[1], a2 = kr[2], a3 = kr[3];
          float sacc = a0.x*qr[0] + a0.y*qr[1] + a0.z*qr[2] + a0.w*qr[3]
                     + a1.x*qr[4] + a1.y*qr[5] + a1.z*qr[6] + a1.w*qr[7]
                     + a2.x*qr[8] + a2.y*qr[9] + a2.z*qr[10] + a2.w*qr[11]
                     + a3.x*qr[12] + a3.y*qr[13] + a3.z*qr[14] + a3.w*qr[15];
          float sc = sacc * 0.25f;            // 1/sqrt(dh=16)
          if (mb[n] != 0) sc = -1e9f;
          scores[hh * SP + n] = sc;
        }
      }
      __syncthreads();

      // Per-head softmax stats: wave `wid` handles heads 2*wid, 2*wid+1
      #pragma unroll
      for (int ho = 0; ho < 2; ++ho) {
        int h2 = 2 * wid + ho;
        float m = -1e30f;
        for (int n = lane; n < NN; n += 64) m = fmaxf(m, scores[h2 * SP + n]);
        m = wmax(m);
        float ss = 0.f;
        for (int n = lane; n < NN; n += 64) {
          float e = __expf(scores[h2 * SP + n] - m);
          scores[h2 * SP + n] = e;
          ss += e;
        }
        ss = wsum(ss);
        if (lane == 0) hsum[h2] = 1.f / ss;
      }
      __syncthreads();

      // Phase B: at = sum_n w[n]*V[n]. 8 row-groups x 32 cols(float4), coalesced rows.
      const int g = t >> 5, c4 = t & 31, hv = c4 >> 2;
      float4 acc = make_float4(0.f, 0.f, 0.f, 0.f);
      for (int n = g; n < NN; n += 8) {
        float w = scores[hv * SP + n];
        const float4 vv = *(const float4*)(Vb + (size_t)n * 384 + c4 * 4);
        acc.x = fmaf(w, vv.x, acc.x);
        acc.y = fmaf(w, vv.y, acc.y);
        acc.z = fmaf(w, vv.z, acc.z);
        acc.w = fmaf(w, vv.w, acc.w);
      }
      *(float4*)(vred + g * DD + c4 * 4) = acc;
      __syncthreads();
      if (t < 128) {
        float at = 0.f;
        #pragma unroll
        for (int gg = 0; gg < 8; ++gg) at += vred[gg * DD + t];
        tmp_s[t] = at * hsum[t >> 4];
      }
      __syncthreads();
    }

    // t2 = h + at@W5 + b5 ; h = LN(t2)
    matvec(Wl + 5 * DD * DD, bl + 5 * DD, tmp_s, h_s, t_s, part, t, false);
    lnorm(t_s, h_s, ln_g + (l * 3 + 1) * DD, ln_b + (l * 3 + 1) * DD, red, t);
    // FFN: h = LN(h + relu(h@W6+b6)@W7 + b7)
    matvec(Wl + 6 * DD * DD, bl + 6 * DD, h_s, nullptr, tmp_s, part, t, true);
    matvec(Wl + 7 * DD * DD, bl + 7 * DD, tmp_s, h_s, t_s, part, t, false);
    lnorm(t_s, h_s, ln_g + (l * 3 + 2) * DD, ln_b + (l * 3 + 2) * DD, red, t);
  }

  // ---- Final layer: single-head attention weights with clip ----
  matvec(Wq, bq, h_s, nullptr, q_s, part, t, false);
  {
    const float* Kb = K_att + (size_t)b * NN * 384 + 2 * DD;
    const int nl0 = t >> 3, p8 = t & 7;
    float qr[16];
    #pragma unroll
    for (int k = 0; k < 16; ++k) qr[k] = q_s[p8 * 16 + k];
    float* fs = scores;  // reuse row 0
    for (int base = 0; base < 1024; base += 32) {
      int n = base + nl0;
      float sacc = 0.f;
      if (n < NN) {
        const float4* kr = (const float4*)(Kb + (size_t)n * 384 + p8 * 16);
        float4 a0 = kr[0], a1 = kr[1], a2 = kr[2], a3 = kr[3];
        sacc = a0.x*qr[0] + a0.y*qr[1] + a0.z*qr[2] + a0.w*qr[3]
             + a1.x*qr[4] + a1.y*qr[5] + a1.z*qr[6] + a1.w*qr[7]
             + a2.x*qr[8] + a2.y*qr[9] + a2.z*qr[10] + a2.w*qr[11]
             + a3.x*qr[12] + a3.y*qr[13] + a3.z*qr[14] + a3.w*qr[15];
      }
      // sum 8 partials (8 consecutive lanes share a row)
      sacc += __shfl_xor(sacc, 1, 64);
      sacc += __shfl_xor(sacc, 2, 64);
      sacc += __shfl_xor(sacc, 4, 64);
      if (n < NN && p8 == 0) {
        float sc = sacc * 0.08838834764831845f;   // 1/sqrt(128)
        sc = 10.f * tanhf(sc);
        if (mb[n] != 0) sc = -1e9f;
        fs[n] = sc;
      }
    }
    __syncthreads();

    float m = -1e30f;
    for (int n = t; n < NN; n += 256) m = fmaxf(m, fs[n]);
    m = wmax(m);
    if (lane == 0) red[wid] = m;
    __syncthreads();
    m = fmaxf(fmaxf(red[0], red[1]), fmaxf(red[2], red[3]));
    float ss = 0.f;
    for (int n = t; n < NN; n += 256) {
      float e = __expf(fs[n] - m);
      fs[n] = e;
      ss += e;
    }
    ss = wsum(ss);
    if (lane == 0) red[4 + wid] = ss;
    __syncthreads();
    float inv = 1.f / (red[4] + red[5] + red[6] + red[7]);
    for (int n = t; n < NN; n += 256) out[(size_t)b * NN + n] = fs[n] * inv;
  }
}

extern "C" void kernel_launch(void* const* d_in, const int* in_sizes, int n_in,
                              void* d_out, int out_size, void* d_ws, size_t ws_size,
                              hipStream_t stream) {
  const float* h_t   = (const float*)d_in[0];
  const float* K_att = (const float*)d_in[1];
  const float* V_att = (const float*)d_in[2];
  const int*   mask  = (const int*)d_in[3];
  const float* W     = (const float*)d_in[4];
  const float* bW    = (const float*)d_in[5];
  const float* ln_g  = (const float*)d_in[6];
  const float* ln_b  = (const float*)d_in[7];
  const float* Wq    = (const float*)d_in[8];
  const float* bq    = (const float*)d_in[9];
  float* out = (float*)d_out;

  hipLaunchKernelGGL(attn_model_kernel, dim3(NB), dim3(256), 0, stream,
                     h_t, K_att, V_att, mask, W, bW, ln_g, ln_b, Wq, bq, out);
}

// Round 2
// 748.940 us; speedup vs baseline: 1.1588x; 1.1588x over previous
//
#include <hip/hip_runtime.h>
#include <math.h>

#define NB 256
#define NN 1001
#define DD 128
#define SP 1008   // padded score row stride
#define BT 1024   // block threads: 16 waves -> 50% occupancy at 1 block/CU

__device__ __forceinline__ float wsum(float v) {
  #pragma unroll
  for (int off = 32; off > 0; off >>= 1) v += __shfl_xor(v, off, 64);
  return v;
}
__device__ __forceinline__ float wmax(float v) {
  #pragma unroll
  for (int off = 32; off > 0; off >>= 1) v = fmaxf(v, __shfl_xor(v, off, 64));
  return v;
}

// out[j] = bias[j] + sum_i in[i]*Wm[i*128+j]  (+res[j]) (relu optional)
// 1024 threads: j = t&127, i-slice = t>>7 (8 slices x 16). Coalesced W columns.
__device__ void matvec(const float* __restrict__ Wm, const float* __restrict__ bias,
                       const float* in_s, const float* res_s, float* out_s,
                       float* part, int t, bool relu) {
  const int j = t & 127;
  const int slice = t >> 7;                       // 0..7
  const float* __restrict__ col = Wm + (size_t)slice * 16 * DD + j;
  const float* in = in_s + slice * 16;
  float acc = 0.f;
  #pragma unroll
  for (int i = 0; i < 16; ++i) acc = fmaf(in[i], col[(size_t)i * DD], acc);
  part[t] = acc;
  __syncthreads();
  if (t < 128) {
    float v = bias[t];
    #pragma unroll
    for (int g = 0; g < 8; ++g) v += part[t + g * 128];
    if (res_s) v += res_s[t];
    if (relu) v = fmaxf(v, 0.f);
    out_s[t] = v;
  }
  __syncthreads();
}

// h_s = LN(t_s)*g + b over 128 elems (biased var, eps 1e-5). Waves 0-1 active.
__device__ void lnorm(const float* t_s, float* h_s, const float* __restrict__ g,
                      const float* __restrict__ bb, float* red, int t) {
  const int wid = t >> 6, lane = t & 63;
  float x = (t < 128) ? t_s[t] : 0.f;
  float s = wsum(x);
  if (lane == 0) red[wid] = s;
  __syncthreads();
  float mean = (red[0] + red[1]) * (1.f / 128.f);
  float d = (t < 128) ? (x - mean) : 0.f;
  float s2 = wsum(d * d);
  if (lane == 0) red[wid] = s2;
  __syncthreads();
  float var = (red[0] + red[1]) * (1.f / 128.f);
  if (t < 128) h_s[t] = d * rsqrtf(var + 1e-5f) * g[t] + bb[t];
  __syncthreads();
}

extern "C" __global__ void __launch_bounds__(BT)
attn_model_kernel(const float* __restrict__ h_t, const float* __restrict__ K_att,
                  const float* __restrict__ V_att, const int* __restrict__ mask,
                  const float* __restrict__ W, const float* __restrict__ bW,
                  const float* __restrict__ ln_g, const float* __restrict__ ln_b,
                  const float* __restrict__ Wq, const float* __restrict__ bq,
                  float* __restrict__ out) {
  __shared__ __align__(16) float scores[8 * SP];   // 32.2 KB
  __shared__ __align__(16) float vred[32 * DD];    // 16 KB
  __shared__ float part[BT];                       // 4 KB
  __shared__ float h_s[DD], q_s[DD], tmp_s[DD], t_s[DD];
  __shared__ float wred[16], wred2[16];
  __shared__ float hsum[8];

  const int t = threadIdx.x;
  const int b = blockIdx.x;
  const int wid = t >> 6, lane = t & 63;

  if (t < 128) h_s[t] = h_t[(size_t)b * DD + t];
  __syncthreads();

  const int* __restrict__ mb = mask + (size_t)b * NN;

  for (int l = 0; l < 2; ++l) {
    const float* Wl = W + (size_t)l * 8 * DD * DD;
    const float* bl = bW + (size_t)l * 8 * DD;

    // self-attn with S=1 collapses: sa = v_sa = h@W2+b2
    matvec(Wl + 2 * DD * DD, bl + 2 * DD, h_s, nullptr, tmp_s, part, t, false);
    // t1 = h + v_sa@W3 + b3 ; h = LN(t1)
    matvec(Wl + 3 * DD * DD, bl + 3 * DD, tmp_s, h_s, t_s, part, t, false);
    lnorm(t_s, h_s, ln_g + (l * 3 + 0) * DD, ln_b + (l * 3 + 0) * DD, wred, t);
    // q = h@W4 + b4
    matvec(Wl + 4 * DD * DD, bl + 4 * DD, h_s, nullptr, q_s, part, t, false);

    // ---- 8-head cross attention, single query, K/V rows stride 384 floats ----
    const float* Kb = K_att + (size_t)b * NN * 384 + l * DD;
    const float* Vb = V_att + (size_t)b * NN * 384 + l * DD;
    {
      // Phase A: scores. thread -> (row = t>>3, head = t&7); 128 rows/iter.
      const int nl0 = t >> 3, hh = t & 7;
      float qr[16];
      #pragma unroll
      for (int k = 0; k < 16; ++k) qr[k] = q_s[hh * 16 + k];
      #pragma unroll
      for (int base = 0; base < 1024; base += 128) {
        int n = base + nl0;
        if (n < NN) {
          const float4* kr = (const float4*)(Kb + (size_t)n * 384 + hh * 16);
          float4 a0 = kr[0], a1 = kr[1], a2 = kr[2], a3 = kr[3];
          float sacc = a0.x*qr[0] + a0.y*qr[1] + a0.z*qr[2] + a0.w*qr[3]
                     + a1.x*qr[4] + a1.y*qr[5] + a1.z*qr[6] + a1.w*qr[7]
                     + a2.x*qr[8] + a2.y*qr[9] + a2.z*qr[10] + a2.w*qr[11]
                     + a3.x*qr[12] + a3.y*qr[13] + a3.z*qr[14] + a3.w*qr[15];
          float sc = sacc * 0.25f;            // 1/sqrt(dh=16)
          if (mb[n] != 0) sc = -1e9f;
          scores[hh * SP + n] = sc;
        }
      }
      __syncthreads();

      // Per-head softmax: head = wid>>1, n-half = wid&1 (16 waves, 2/head)
      {
        const int h2 = wid >> 1, half = wid & 1;
        float m = -1e30f;
        for (int n = 64 * half + lane; n < NN; n += 128)
          m = fmaxf(m, scores[h2 * SP + n]);
        m = wmax(m);
        if (lane == 0) wred[wid] = m;
        __syncthreads();
        float mm = fmaxf(wred[2 * h2], wred[2 * h2 + 1]);
        float ss = 0.f;
        for (int n = 64 * half + lane; n < NN; n += 128) {
          float e = __expf(scores[h2 * SP + n] - mm);
          scores[h2 * SP + n] = e;
          ss += e;
        }
        ss = wsum(ss);
        if (lane == 0) wred2[wid] = ss;
        __syncthreads();
        if (t < 8) hsum[t] = 1.f / (wred2[2 * t] + wred2[2 * t + 1]);
        __syncthreads();
      }

      // Phase B: at = sum_n w[n]*V[n]. 32 row-groups x 32 cols(float4).
      const int g = t >> 5, c4 = t & 31, hv = c4 >> 2;
      float4 acc = make_float4(0.f, 0.f, 0.f, 0.f);
      for (int n = g; n < NN; n += 32) {
        float w = scores[hv * SP + n];
        const float4 vv = *(const float4*)(Vb + (size_t)n * 384 + c4 * 4);
        acc.x = fmaf(w, vv.x, acc.x);
        acc.y = fmaf(w, vv.y, acc.y);
        acc.z = fmaf(w, vv.z, acc.z);
        acc.w = fmaf(w, vv.w, acc.w);
      }
      *(float4*)(vred + g * DD + c4 * 4) = acc;
      __syncthreads();
      if (t < 128) {
        float at = 0.f;
        #pragma unroll
        for (int gg = 0; gg < 32; ++gg) at += vred[gg * DD + t];
        tmp_s[t] = at * hsum[t >> 4];
      }
      __syncthreads();
    }

    // t2 = h + at@W5 + b5 ; h = LN(t2)
    matvec(Wl + 5 * DD * DD, bl + 5 * DD, tmp_s, h_s, t_s, part, t, false);
    lnorm(t_s, h_s, ln_g + (l * 3 + 1) * DD, ln_b + (l * 3 + 1) * DD, wred, t);
    // FFN: h = LN(h + relu(h@W6+b6)@W7 + b7)
    matvec(Wl + 6 * DD * DD, bl + 6 * DD, h_s, nullptr, tmp_s, part, t, true);
    matvec(Wl + 7 * DD * DD, bl + 7 * DD, tmp_s, h_s, t_s, part, t, false);
    lnorm(t_s, h_s, ln_g + (l * 3 + 2) * DD, ln_b + (l * 3 + 2) * DD, wred, t);
  }

  // ---- Final layer: single-head attention weights with clip ----
  matvec(Wq, bq, h_s, nullptr, q_s, part, t, false);
  {
    const float* Kb = K_att + (size_t)b * NN * 384 + 2 * DD;
    const int nl0 = t >> 3, p8 = t & 7;
    float qr[16];
    #pragma unroll
    for (int k = 0; k < 16; ++k) qr[k] = q_s[p8 * 16 + k];
    float* fs = scores;  // reuse row 0
    #pragma unroll
    for (int base = 0; base < 1024; base += 128) {
      int n = base + nl0;
      float sacc = 0.f;
      if (n < NN) {
        const float4* kr = (const float4*)(Kb + (size_t)n * 384 + p8 * 16);
        float4 a0 = kr[0], a1 = kr[1], a2 = kr[2], a3 = kr[3];
        sacc = a0.x*qr[0] + a0.y*qr[1] + a0.z*qr[2] + a0.w*qr[3]
             + a1.x*qr[4] + a1.y*qr[5] + a1.z*qr[6] + a1.w*qr[7]
             + a2.x*qr[8] + a2.y*qr[9] + a2.z*qr[10] + a2.w*qr[11]
             + a3.x*qr[12] + a3.y*qr[13] + a3.z*qr[14] + a3.w*qr[15];
      }
      // sum 8 partials (8 consecutive lanes share a row)
      sacc += __shfl_xor(sacc, 1, 64);
      sacc += __shfl_xor(sacc, 2, 64);
      sacc += __shfl_xor(sacc, 4, 64);
      if (n < NN && p8 == 0) {
        float sc = sacc * 0.08838834764831845f;   // 1/sqrt(128)
        sc = 10.f * tanhf(sc);
        if (mb[n] != 0) sc = -1e9f;
        fs[n] = sc;
      }
    }
    __syncthreads();

    // softmax over 1001 with 1024 threads (one element each)
    float v = (t < NN) ? fs[t] : -1e30f;
    float m = wmax(v);
    if (lane == 0) wred[wid] = m;
    __syncthreads();
    float mm = -1e30f;
    #pragma unroll
    for (int i = 0; i < 16; ++i) mm = fmaxf(mm, wred[i]);
    float e = (t < NN) ? __expf(v - mm) : 0.f;
    float ss = wsum(e);
    if (lane == 0) wred2[wid] = ss;
    __syncthreads();
    float tot = 0.f;
    #pragma unroll
    for (int i = 0; i < 16; ++i) tot += wred2[i];
    if (t < NN) out[(size_t)b * NN + t] = e * (1.f / tot);
  }
}

extern "C" void kernel_launch(void* const* d_in, const int* in_sizes, int n_in,
                              void* d_out, int out_size, void* d_ws, size_t ws_size,
                              hipStream_t stream) {
  const float* h_t   = (const float*)d_in[0];
  const float* K_att = (const float*)d_in[1];
  const float* V_att = (const float*)d_in[2];
  const int*   mask  = (const int*)d_in[3];
  const float* W     = (const float*)d_in[4];
  const float* bW    = (const float*)d_in[5];
  const float* ln_g  = (const float*)d_in[6];
  const float* ln_b  = (const float*)d_in[7];
  const float* Wq    = (const float*)d_in[8];
  const float* bq    = (const float*)d_in[9];
  float* out = (float*)d_out;

  hipLaunchKernelGGL(attn_model_kernel, dim3(NB), dim3(BT), 0, stream,
                     h_t, K_att, V_att, mask, W, bW, ln_g, ln_b, Wq, bq, out);
}